// Round 10
// baseline (45.174 us; speedup 1.0000x reference)
//
#include <hip/hip_runtime.h>
#include <math.h>

#define LDIM 64
#define QTW 8     // queries per (1-wave) block
#define WMAX 12   // rel-chunk slots per query tile
#define LOG2E 1.4426950408889634f

static __device__ __forceinline__ float fast_exp2(float x) {
#if __has_builtin(__builtin_amdgcn_exp2f)
    return __builtin_amdgcn_exp2f(x);
#else
    return exp2f(x);
#endif
}

static __device__ __forceinline__ float4 ld4(const float* p) {
    return *(const float4*)p;
}

// K1: precompute everything off the hot path.
//   Bi[c][g][o]  = float4{ B[4g+j][o] } obs-side preact (0-padded past No)
//   A4[q*16+g]   = float4 query-side preact for l=4g..4g+3
//   P4[o]        = (x,y,z, mask ? batch+1 : 0)
//   w2s4[g]      = W2[4g..4g+3] * log2e
//   qwin[t]      = chunk-granular window [cs,ce] for query tile t (QTW queries)
//   zero acc/den
__global__ __launch_bounds__(256) void gano_pre(
    const float* __restrict__ pos_obs, const float* __restrict__ pos_query,
    const float* __restrict__ W1, const float* __restrict__ b1,
    const float* __restrict__ W2,
    const int* __restrict__ obs_mask, const int* __restrict__ obs_batch,
    const int* __restrict__ query_batch,
    float4* __restrict__ Bi, float4* __restrict__ A4, float4* __restrict__ P4,
    float4* __restrict__ w2s4, int2* __restrict__ qwin, float* __restrict__ zeroR,
    int No, int NoA, int Nq, int nC, int nQT, int zn)
{
    const int gid = blockIdx.x * blockDim.x + threadIdx.x;

    // Bi
    if (gid < NoA * 16) {
        const int o = gid & 63, g = (gid >> 6) & 15, c = gid >> 10;
        const int oo = (c << 6) + o;
        float4 r = make_float4(0.f, 0.f, 0.f, 0.f);
        if (oo < No) {
            const float px = pos_obs[oo*3+0], py = pos_obs[oo*3+1], pz = pos_obs[oo*3+2];
            const float4 b0 = ld4(b1 + 4*g);
            const float4 u3 = ld4(W1 + 3*LDIM + 4*g), u6 = ld4(W1 + 6*LDIM + 4*g);
            const float4 u4 = ld4(W1 + 4*LDIM + 4*g), u7 = ld4(W1 + 7*LDIM + 4*g);
            const float4 u5 = ld4(W1 + 5*LDIM + 4*g), u8 = ld4(W1 + 8*LDIM + 4*g);
            r.x = fmaf(px, u3.x-u6.x, fmaf(py, u4.x-u7.x, fmaf(pz, u5.x-u8.x, b0.x)));
            r.y = fmaf(px, u3.y-u6.y, fmaf(py, u4.y-u7.y, fmaf(pz, u5.y-u8.y, b0.y)));
            r.z = fmaf(px, u3.z-u6.z, fmaf(py, u4.z-u7.z, fmaf(pz, u5.z-u8.z, b0.z)));
            r.w = fmaf(px, u3.w-u6.w, fmaf(py, u4.w-u7.w, fmaf(pz, u5.w-u8.w, b0.w)));
        }
        Bi[gid] = r;
    }
    // A4
    if (gid < Nq * 16) {
        const int q = gid >> 4, g = gid & 15;
        const float px = pos_query[q*3+0], py = pos_query[q*3+1], pz = pos_query[q*3+2];
        const float4 u0 = ld4(W1 + 0*LDIM + 4*g), u6 = ld4(W1 + 6*LDIM + 4*g);
        const float4 u1 = ld4(W1 + 1*LDIM + 4*g), u7 = ld4(W1 + 7*LDIM + 4*g);
        const float4 u2 = ld4(W1 + 2*LDIM + 4*g), u8 = ld4(W1 + 8*LDIM + 4*g);
        float4 r;
        r.x = fmaf(px, u0.x+u6.x, fmaf(py, u1.x+u7.x, pz*(u2.x+u8.x)));
        r.y = fmaf(px, u0.y+u6.y, fmaf(py, u1.y+u7.y, pz*(u2.y+u8.y)));
        r.z = fmaf(px, u0.z+u6.z, fmaf(py, u1.z+u7.z, pz*(u2.z+u8.z)));
        r.w = fmaf(px, u0.w+u6.w, fmaf(py, u1.w+u7.w, pz*(u2.w+u8.w)));
        A4[gid] = r;
    }
    // P4
    if (gid < NoA) {
        float4 pp = make_float4(0.f, 0.f, 0.f, 0.f);
        if (gid < No)
            pp = make_float4(pos_obs[gid*3+0], pos_obs[gid*3+1], pos_obs[gid*3+2],
                             obs_mask[gid] ? (float)(obs_batch[gid] + 1) : 0.0f);
        P4[gid] = pp;
    }
    // w2s4
    if (gid < 16) {
        const float4 w = ld4(W2 + 4 * gid);
        w2s4[gid] = make_float4(w.x * LOG2E, w.y * LOG2E, w.z * LOG2E, w.w * LOG2E);
    }
    // qwin
    if (gid < nQT) {
        const int q0 = gid * QTW;
        const int t_lo = query_batch[min(q0, Nq - 1)];
        const int t_hi = query_batch[min(q0 + QTW - 1, Nq - 1)];
        int lo = 0, hi = nC;
        while (lo < hi) { int mid = (lo + hi) >> 1;
            if (obs_batch[min(mid * 64 + 63, No - 1)] < t_lo) lo = mid + 1; else hi = mid; }
        const int cs = lo;
        lo = 0; hi = nC;
        while (lo < hi) { int mid = (lo + hi) >> 1;
            if (obs_batch[min(mid * 64, No - 1)] <= t_hi) lo = mid + 1; else hi = mid; }
        qwin[gid] = make_int2(cs, lo - 1);   // empty window if cs > ce
    }
    // zero acc/den
    if (gid < zn) zeroR[gid] = 0.0f;
}

// K2: one WAVE per (8-query tile, rel-chunk slot). No barriers. Logits
// (lane=obs, Bi float4 stream), no-max e (validated R6-R9), PV accumulates
// h_obs directly (Wv applied in K3), register accumulation across chunks,
// one plain-atomic writeback per wave. Strided c-loop covers any window.
__global__ __launch_bounds__(64) void gano_accum(
    const float* __restrict__ h_obs,
    const float4* __restrict__ Bi, const float4* __restrict__ A4,
    const float4* __restrict__ P4, const float4* __restrict__ w2s4,
    const float* __restrict__ pos_query, const int* __restrict__ query_batch,
    const int2* __restrict__ qwin,
    float* __restrict__ acc, float* __restrict__ den,
    int No, int Nq)
{
    const int rel = blockIdx.x;
    const int qt  = blockIdx.y;
    const int q0  = qt * QTW;
    const int lane = threadIdx.x;

    const int2 w = qwin[qt];
    if (w.x + rel > w.y) return;

    __shared__ float4 a4[QTW][16];
    __shared__ float4 w2l[16];
    __shared__ float4 qp4[QTW];
    __shared__ float  e_lds[QTW][LDIM];

    // ---- wave-private staging (no barrier: within-wave LDS is in-order) ----
    if (lane < 16) w2l[lane] = w2s4[lane];
    if (lane < QTW) {
        const int q = min(q0 + lane, Nq - 1);
        qp4[lane] = make_float4(pos_query[q*3+0], pos_query[q*3+1], pos_query[q*3+2],
                                (float)(query_batch[q] + 1));
    }
    {
        const int i0 = lane, i1 = lane + 64;
        a4[i0 >> 4][i0 & 15] = A4[(size_t)q0 * 16 + i0];
        a4[i1 >> 4][i1 & 15] = A4[(size_t)q0 * 16 + i1];
    }

    float den_a[QTW], pacc[QTW];
    #pragma unroll
    for (int j = 0; j < QTW; ++j) { den_a[j] = 0.0f; pacc[j] = 0.0f; }

    for (int c = w.x + rel; c <= w.y; c += WMAX) {
        const float4 p = P4[(c << 6) + lane];
        const float4* Bc = Bi + ((size_t)c << 10) + lane;

        // ---- logits: lane = obs, 8 queries ----
        float lg[QTW];
        #pragma unroll
        for (int j = 0; j < QTW; ++j) lg[j] = 0.0f;
        #pragma unroll
        for (int g = 0; g < 16; ++g) {
            const float4 Bv = Bc[g << 6];
            const float4 wv = w2l[g];
            #pragma unroll
            for (int j = 0; j < QTW; ++j) {
                const float4 a = a4[j][g];
                lg[j] = fmaf(fmaxf(a.x + Bv.x, 0.f), wv.x, lg[j]);
                lg[j] = fmaf(fmaxf(a.y + Bv.y, 0.f), wv.y, lg[j]);
                lg[j] = fmaf(fmaxf(a.z + Bv.z, 0.f), wv.z, lg[j]);
                lg[j] = fmaf(fmaxf(a.w + Bv.w, 0.f), wv.w, lg[j]);
            }
        }

        // ---- mask + direct exp2; e to wave-private LDS; reuse lg as ds ----
        #pragma unroll
        for (int j = 0; j < QTW; ++j) {
            const float4 qp = qp4[j];
            const float dx = qp.x - p.x, dy = qp.y - p.y, dz = qp.z - p.z;
            const float d2 = fmaf(dz, dz, fmaf(dy, dy, dx * dx));
            const bool valid = (p.w == qp.w) & (d2 <= 1.0f);
            const float e = valid ? fast_exp2(lg[j]) : 0.0f;
            e_lds[j][lane] = e;
            lg[j] = e;
        }
        #pragma unroll
        for (int msk = 32; msk; msk >>= 1) {
            #pragma unroll
            for (int j = 0; j < QTW; ++j) lg[j] += __shfl_xor(lg[j], msk, 64);
        }
        #pragma unroll
        for (int j = 0; j < QTW; ++j) den_a[j] += lg[j];

        // ---- PV: lane = hidden-input dim k, 8-deep load batches ----
        const float* Hc = h_obs + ((size_t)c << 12) + lane;
        if ((c << 6) + 64 <= No) {
            for (int oo = 0; oo < LDIM; oo += 8) {
                const float v0 = Hc[(oo + 0) << 6];
                const float v1 = Hc[(oo + 1) << 6];
                const float v2 = Hc[(oo + 2) << 6];
                const float v3 = Hc[(oo + 3) << 6];
                const float v4 = Hc[(oo + 4) << 6];
                const float v5 = Hc[(oo + 5) << 6];
                const float v6 = Hc[(oo + 6) << 6];
                const float v7 = Hc[(oo + 7) << 6];
                #pragma unroll
                for (int j = 0; j < QTW; ++j) {
                    const float4 ea = *(const float4*)&e_lds[j][oo];
                    const float4 eb = *(const float4*)&e_lds[j][oo + 4];
                    float s = pacc[j];
                    s = fmaf(ea.x, v0, s); s = fmaf(ea.y, v1, s);
                    s = fmaf(ea.z, v2, s); s = fmaf(ea.w, v3, s);
                    s = fmaf(eb.x, v4, s); s = fmaf(eb.y, v5, s);
                    s = fmaf(eb.z, v6, s); s = fmaf(eb.w, v7, s);
                    pacc[j] = s;
                }
            }
        } else {  // tail chunk (only if No % 64 != 0): clamp rows, e=0 there
            for (int oo = 0; oo < LDIM; ++oo) {
                const int orow = min((c << 6) + oo, No - 1);
                const float v = h_obs[((size_t)orow << 6) + lane];
                #pragma unroll
                for (int j = 0; j < QTW; ++j)
                    pacc[j] = fmaf(e_lds[j][oo], v, pacc[j]);
            }
        }
    }

    // ---- writeback: plain fire-and-forget atomics (R8 lesson: no fences) ----
    if (lane == 0) {
        #pragma unroll
        for (int j = 0; j < QTW; ++j)
            if (q0 + j < Nq) atomicAdd(&den[q0 + j], den_a[j]);
    }
    #pragma unroll
    for (int j = 0; j < QTW; ++j)
        if (q0 + j < Nq) atomicAdd(&acc[(size_t)(q0 + j) * LDIM + lane], pacc[j]);
}

// K3: normalize + Wv epilogue + bv.  out[q] = (acc[q]/D) @ Wv + bv, or 0 if D==0.
__global__ __launch_bounds__(256) void gano_norm(
    const float* __restrict__ acc, const float* __restrict__ den,
    const float* __restrict__ Wv, const float* __restrict__ bv,
    float* __restrict__ out, int Nq)
{
    const int tid = threadIdx.x, lane = tid & 63, wid = tid >> 6;
    const int q0 = blockIdx.x * 8 + wid * 2;
    if (q0 >= Nq) return;

    __shared__ float r_lds[4][2][LDIM];

    const float D0 = den[q0];
    const float D1 = (q0 + 1 < Nq) ? den[q0 + 1] : 0.0f;
    const float rd0 = (D0 > 0.0f) ? 1.0f / D0 : 0.0f;
    const float rd1 = (D1 > 0.0f) ? 1.0f / D1 : 0.0f;
    r_lds[wid][0][lane] = acc[(size_t)q0 * LDIM + lane] * rd0;
    r_lds[wid][1][lane] = (q0 + 1 < Nq) ? acc[(size_t)(q0 + 1) * LDIM + lane] * rd1 : 0.0f;
    // wave-private: no barrier needed
    float o0 = 0.f, o1 = 0.f;
    #pragma unroll 8
    for (int k = 0; k < LDIM; ++k) {
        const float w = Wv[(k << 6) + lane];
        o0 = fmaf(r_lds[wid][0][k], w, o0);
        o1 = fmaf(r_lds[wid][1][k], w, o1);
    }
    const float b = bv[lane];
    out[(size_t)q0 * LDIM + lane] = (D0 > 0.0f) ? o0 + b : 0.0f;
    if (q0 + 1 < Nq)
        out[(size_t)(q0 + 1) * LDIM + lane] = (D1 > 0.0f) ? o1 + b : 0.0f;
}

extern "C" void kernel_launch(void* const* d_in, const int* in_sizes, int n_in,
                              void* d_out, int out_size, void* d_ws, size_t ws_size,
                              hipStream_t stream) {
    const float* h_obs     = (const float*)d_in[0];
    const float* pos_obs   = (const float*)d_in[1];
    const float* pos_query = (const float*)d_in[2];
    const float* W1        = (const float*)d_in[3];
    const float* b1        = (const float*)d_in[4];
    const float* W2        = (const float*)d_in[5];
    // d_in[6] = b2: constant shift, cancels in softmax -> unused
    const float* Wv        = (const float*)d_in[7];
    const float* bv        = (const float*)d_in[8];
    const int* obs_mask    = (const int*)d_in[9];
    const int* obs_batch   = (const int*)d_in[10];
    const int* query_batch = (const int*)d_in[11];

    const int No  = in_sizes[1] / 3;
    const int Nq  = in_sizes[2] / 3;
    const int NoA = (No + 63) & ~63;
    const int nC  = NoA / 64;
    const int nQT = (Nq + QTW - 1) / QTW;
    const int zn  = Nq * (LDIM + 1);

    // ws layout (~1.1 MB)
    float4* Bi   = (float4*)d_ws;                    // NoA*16 float4
    float4* A4   = Bi + (size_t)NoA * 16;            // Nq*16 float4
    float4* P4   = A4 + (size_t)Nq * 16;             // NoA float4
    float4* w2s4 = P4 + NoA;                         // 16 float4
    int2*   qwin = (int2*)(w2s4 + 16);               // nQT int2
    float*  acc  = (float*)(qwin + nQT);             // Nq*64 f (zeroed)
    float*  den  = acc + (size_t)Nq * LDIM;          // Nq f    (zeroed)

    int gridN = NoA * 16;
    if (Nq * 16 > gridN) gridN = Nq * 16;
    if (zn > gridN) gridN = zn;

    gano_pre<<<(gridN + 255) / 256, 256, 0, stream>>>(
        pos_obs, pos_query, W1, b1, W2, obs_mask, obs_batch, query_batch,
        Bi, A4, P4, w2s4, qwin, acc, No, NoA, Nq, nC, nQT, zn);

    dim3 g2(WMAX, nQT);
    gano_accum<<<g2, 64, 0, stream>>>(
        h_obs, Bi, A4, P4, w2s4, pos_query, query_batch, qwin,
        acc, den, No, Nq);

    gano_norm<<<(Nq + 7) / 8, 256, 0, stream>>>(acc, den, Wv, bv, (float*)d_out, Nq);
}

// Round 11
// 42.111 us; speedup vs baseline: 1.0728x; 1.0728x over previous
//
#include <hip/hip_runtime.h>
#include <math.h>

#define LDIM 64
#define QTW 8     // queries per tile
#define WSLOT 12  // chunk slots per tile
#define LOG2E 1.4426950408889634f

static __device__ __forceinline__ float fast_exp2(float x) {
#if __has_builtin(__builtin_amdgcn_exp2f)
    return __builtin_amdgcn_exp2f(x);
#else
    return exp2f(x);
#endif
}

static __device__ __forceinline__ float4 ld4(const float* p) {
    return *(const float4*)p;
}

// K1: precompute everything off the hot path.
//   Bi[c][g][o]  = float4{ B[4g+j][o] } obs-side preact (0-padded past No)
//   A4[q*16+g]   = float4 query-side preact
//   P4[o]        = (x,y,z, mask ? batch+1 : 0)
//   w2s4[g]      = W2[4g..4g+3] * log2e
//   qwin[t]      = chunk window [cs,ce] for 8-query tile t
//   zero acc/den
__global__ __launch_bounds__(256) void gano_pre(
    const float* __restrict__ pos_obs, const float* __restrict__ pos_query,
    const float* __restrict__ W1, const float* __restrict__ b1,
    const float* __restrict__ W2,
    const int* __restrict__ obs_mask, const int* __restrict__ obs_batch,
    const int* __restrict__ query_batch,
    float4* __restrict__ Bi, float4* __restrict__ A4, float4* __restrict__ P4,
    float4* __restrict__ w2s4, int2* __restrict__ qwin, float* __restrict__ zeroR,
    int No, int NoA, int Nq, int nC, int nQT, int zn)
{
    const int gid = blockIdx.x * blockDim.x + threadIdx.x;

    // Bi
    if (gid < NoA * 16) {
        const int o = gid & 63, g = (gid >> 6) & 15, c = gid >> 10;
        const int oo = (c << 6) + o;
        float4 r = make_float4(0.f, 0.f, 0.f, 0.f);
        if (oo < No) {
            const float px = pos_obs[oo*3+0], py = pos_obs[oo*3+1], pz = pos_obs[oo*3+2];
            const float4 b0 = ld4(b1 + 4*g);
            const float4 u3 = ld4(W1 + 3*LDIM + 4*g), u6 = ld4(W1 + 6*LDIM + 4*g);
            const float4 u4 = ld4(W1 + 4*LDIM + 4*g), u7 = ld4(W1 + 7*LDIM + 4*g);
            const float4 u5 = ld4(W1 + 5*LDIM + 4*g), u8 = ld4(W1 + 8*LDIM + 4*g);
            r.x = fmaf(px, u3.x-u6.x, fmaf(py, u4.x-u7.x, fmaf(pz, u5.x-u8.x, b0.x)));
            r.y = fmaf(px, u3.y-u6.y, fmaf(py, u4.y-u7.y, fmaf(pz, u5.y-u8.y, b0.y)));
            r.z = fmaf(px, u3.z-u6.z, fmaf(py, u4.z-u7.z, fmaf(pz, u5.z-u8.z, b0.z)));
            r.w = fmaf(px, u3.w-u6.w, fmaf(py, u4.w-u7.w, fmaf(pz, u5.w-u8.w, b0.w)));
        }
        Bi[gid] = r;
    }
    // A4
    if (gid < Nq * 16) {
        const int q = gid >> 4, g = gid & 15;
        const float px = pos_query[q*3+0], py = pos_query[q*3+1], pz = pos_query[q*3+2];
        const float4 u0 = ld4(W1 + 0*LDIM + 4*g), u6 = ld4(W1 + 6*LDIM + 4*g);
        const float4 u1 = ld4(W1 + 1*LDIM + 4*g), u7 = ld4(W1 + 7*LDIM + 4*g);
        const float4 u2 = ld4(W1 + 2*LDIM + 4*g), u8 = ld4(W1 + 8*LDIM + 4*g);
        float4 r;
        r.x = fmaf(px, u0.x+u6.x, fmaf(py, u1.x+u7.x, pz*(u2.x+u8.x)));
        r.y = fmaf(px, u0.y+u6.y, fmaf(py, u1.y+u7.y, pz*(u2.y+u8.y)));
        r.z = fmaf(px, u0.z+u6.z, fmaf(py, u1.z+u7.z, pz*(u2.z+u8.z)));
        r.w = fmaf(px, u0.w+u6.w, fmaf(py, u1.w+u7.w, pz*(u2.w+u8.w)));
        A4[gid] = r;
    }
    // P4
    if (gid < NoA) {
        float4 pp = make_float4(0.f, 0.f, 0.f, 0.f);
        if (gid < No)
            pp = make_float4(pos_obs[gid*3+0], pos_obs[gid*3+1], pos_obs[gid*3+2],
                             obs_mask[gid] ? (float)(obs_batch[gid] + 1) : 0.0f);
        P4[gid] = pp;
    }
    // w2s4
    if (gid < 16) {
        const float4 w = ld4(W2 + 4 * gid);
        w2s4[gid] = make_float4(w.x * LOG2E, w.y * LOG2E, w.z * LOG2E, w.w * LOG2E);
    }
    // qwin
    if (gid < nQT) {
        const int q0 = gid * QTW;
        const int t_lo = query_batch[min(q0, Nq - 1)];
        const int t_hi = query_batch[min(q0 + QTW - 1, Nq - 1)];
        int lo = 0, hi = nC;
        while (lo < hi) { int mid = (lo + hi) >> 1;
            if (obs_batch[min(mid * 64 + 63, No - 1)] < t_lo) lo = mid + 1; else hi = mid; }
        const int cs = lo;
        lo = 0; hi = nC;
        while (lo < hi) { int mid = (lo + hi) >> 1;
            if (obs_batch[min(mid * 64, No - 1)] <= t_hi) lo = mid + 1; else hi = mid; }
        qwin[gid] = make_int2(cs, lo - 1);   // empty if cs > ce
    }
    // zero acc/den
    if (gid < zn) zeroR[gid] = 0.0f;
}

// K2: block (slot s, tile t) = 256 thr / 4 waves; block handles chunk cs+s
// (strided loop for wide windows). Wave wid owns queries {2*wid, 2*wid+1}
// of the tile: tiny register state (VGPR low -> high occupancy), short
// per-chunk chains. One barrier (a4 staging); wave-private e_lds after.
// no-max e (validated R6-R10); h_obs accumulated directly (Wv in K3);
// plain fire-and-forget atomics (R8 lesson: no fences).
__global__ __launch_bounds__(256) void gano_accum(
    const float* __restrict__ h_obs,
    const float4* __restrict__ Bi, const float4* __restrict__ A4,
    const float4* __restrict__ P4, const float4* __restrict__ w2s4,
    const float* __restrict__ pos_query, const int* __restrict__ query_batch,
    const int2* __restrict__ qwin,
    float* __restrict__ acc, float* __restrict__ den,
    int No, int Nq)
{
    const int s   = blockIdx.x;
    const int qt  = blockIdx.y;
    const int q0  = qt * QTW;
    const int tid = threadIdx.x, lane = tid & 63, wid = tid >> 6;

    const int2 w = qwin[qt];
    if (w.x + s > w.y) return;

    __shared__ float4 a4[QTW][16];
    __shared__ float4 w2l[16];
    __shared__ float4 qp4[QTW];
    __shared__ float  e_lds[4][2][LDIM];

    if (tid < QTW * 16)
        a4[tid >> 4][tid & 15] = A4[(size_t)q0 * 16 + tid];
    else if (tid < QTW * 16 + 16)
        w2l[tid - QTW * 16] = w2s4[tid - QTW * 16];
    else if (tid < QTW * 16 + 16 + QTW) {
        const int j = tid - QTW * 16 - 16;
        const int q = min(q0 + j, Nq - 1);
        qp4[j] = make_float4(pos_query[q*3+0], pos_query[q*3+1], pos_query[q*3+2],
                             (float)(query_batch[q] + 1));
    }
    __syncthreads();

    const int j0 = wid * 2, j1 = wid * 2 + 1;
    const float4 qpA = qp4[j0], qpB = qp4[j1];

    float denA = 0.f, denB = 0.f, paccA = 0.f, paccB = 0.f;

    for (int c = w.x + s; c <= w.y; c += WSLOT) {
        const float4 p = P4[(c << 6) + lane];
        const float4* Bc = Bi + ((size_t)c << 10) + lane;

        // ---- logits: lane = obs, 2 queries ----
        float lgA = 0.f, lgB = 0.f;
        #pragma unroll
        for (int g = 0; g < 16; ++g) {
            const float4 Bv = Bc[g << 6];
            const float4 wv = w2l[g];
            const float4 aA = a4[j0][g];
            const float4 aB = a4[j1][g];
            lgA = fmaf(fmaxf(aA.x + Bv.x, 0.f), wv.x, lgA);
            lgB = fmaf(fmaxf(aB.x + Bv.x, 0.f), wv.x, lgB);
            lgA = fmaf(fmaxf(aA.y + Bv.y, 0.f), wv.y, lgA);
            lgB = fmaf(fmaxf(aB.y + Bv.y, 0.f), wv.y, lgB);
            lgA = fmaf(fmaxf(aA.z + Bv.z, 0.f), wv.z, lgA);
            lgB = fmaf(fmaxf(aB.z + Bv.z, 0.f), wv.z, lgB);
            lgA = fmaf(fmaxf(aA.w + Bv.w, 0.f), wv.w, lgA);
            lgB = fmaf(fmaxf(aB.w + Bv.w, 0.f), wv.w, lgB);
        }

        // ---- mask + direct exp2 ----
        float eA, eB;
        {
            const float dx = qpA.x - p.x, dy = qpA.y - p.y, dz = qpA.z - p.z;
            const float d2 = fmaf(dz, dz, fmaf(dy, dy, dx * dx));
            eA = ((p.w == qpA.w) & (d2 <= 1.0f)) ? fast_exp2(lgA) : 0.0f;
        }
        {
            const float dx = qpB.x - p.x, dy = qpB.y - p.y, dz = qpB.z - p.z;
            const float d2 = fmaf(dz, dz, fmaf(dy, dy, dx * dx));
            eB = ((p.w == qpB.w) & (d2 <= 1.0f)) ? fast_exp2(lgB) : 0.0f;
        }
        e_lds[wid][0][lane] = eA;
        e_lds[wid][1][lane] = eB;
        float dA = eA, dB = eB;
        #pragma unroll
        for (int msk = 32; msk; msk >>= 1) {
            dA += __shfl_xor(dA, msk, 64);
            dB += __shfl_xor(dB, msk, 64);
        }
        denA += dA; denB += dB;

        // ---- PV: lane = hidden-input dim k ----
        const float* Hc = h_obs + ((size_t)c << 12) + lane;
        if ((c << 6) + 64 <= No) {
            #pragma unroll 2
            for (int oo = 0; oo < LDIM; oo += 8) {
                const float v0 = Hc[(oo + 0) << 6];
                const float v1 = Hc[(oo + 1) << 6];
                const float v2 = Hc[(oo + 2) << 6];
                const float v3 = Hc[(oo + 3) << 6];
                const float v4 = Hc[(oo + 4) << 6];
                const float v5 = Hc[(oo + 5) << 6];
                const float v6 = Hc[(oo + 6) << 6];
                const float v7 = Hc[(oo + 7) << 6];
                const float4 ea0 = *(const float4*)&e_lds[wid][0][oo];
                const float4 ea1 = *(const float4*)&e_lds[wid][0][oo + 4];
                const float4 eb0 = *(const float4*)&e_lds[wid][1][oo];
                const float4 eb1 = *(const float4*)&e_lds[wid][1][oo + 4];
                paccA = fmaf(ea0.x, v0, paccA); paccB = fmaf(eb0.x, v0, paccB);
                paccA = fmaf(ea0.y, v1, paccA); paccB = fmaf(eb0.y, v1, paccB);
                paccA = fmaf(ea0.z, v2, paccA); paccB = fmaf(eb0.z, v2, paccB);
                paccA = fmaf(ea0.w, v3, paccA); paccB = fmaf(eb0.w, v3, paccB);
                paccA = fmaf(ea1.x, v4, paccA); paccB = fmaf(eb1.x, v4, paccB);
                paccA = fmaf(ea1.y, v5, paccA); paccB = fmaf(eb1.y, v5, paccB);
                paccA = fmaf(ea1.z, v6, paccA); paccB = fmaf(eb1.z, v6, paccB);
                paccA = fmaf(ea1.w, v7, paccA); paccB = fmaf(eb1.w, v7, paccB);
            }
        } else {  // tail chunk: clamp rows (e is 0 there)
            for (int oo = 0; oo < LDIM; ++oo) {
                const int orow = min((c << 6) + oo, No - 1);
                const float v = h_obs[((size_t)orow << 6) + lane];
                paccA = fmaf(e_lds[wid][0][oo], v, paccA);
                paccB = fmaf(e_lds[wid][1][oo], v, paccB);
            }
        }
    }

    // ---- writeback ----
    if (q0 + j0 < Nq) {
        atomicAdd(&acc[(size_t)(q0 + j0) * LDIM + lane], paccA);
        if (lane == 0) atomicAdd(&den[q0 + j0], denA);
    }
    if (q0 + j1 < Nq) {
        atomicAdd(&acc[(size_t)(q0 + j1) * LDIM + lane], paccB);
        if (lane == 0) atomicAdd(&den[q0 + j1], denB);
    }
}

// K3: normalize + Wv epilogue + bv.  out[q] = (acc[q]/D) @ Wv + bv, or 0 if D==0.
__global__ __launch_bounds__(256) void gano_norm(
    const float* __restrict__ acc, const float* __restrict__ den,
    const float* __restrict__ Wv, const float* __restrict__ bv,
    float* __restrict__ out, int Nq)
{
    const int tid = threadIdx.x, lane = tid & 63, wid = tid >> 6;
    const int q0 = blockIdx.x * 8 + wid * 2;
    if (q0 >= Nq) return;

    __shared__ float r_lds[4][2][LDIM];

    const float D0 = den[q0];
    const float D1 = (q0 + 1 < Nq) ? den[q0 + 1] : 0.0f;
    const float rd0 = (D0 > 0.0f) ? 1.0f / D0 : 0.0f;
    const float rd1 = (D1 > 0.0f) ? 1.0f / D1 : 0.0f;
    r_lds[wid][0][lane] = acc[(size_t)q0 * LDIM + lane] * rd0;
    r_lds[wid][1][lane] = (q0 + 1 < Nq) ? acc[(size_t)(q0 + 1) * LDIM + lane] * rd1 : 0.0f;
    // wave-private: no barrier needed
    float o0 = 0.f, o1 = 0.f;
    #pragma unroll 8
    for (int k = 0; k < LDIM; ++k) {
        const float w = Wv[(k << 6) + lane];
        o0 = fmaf(r_lds[wid][0][k], w, o0);
        o1 = fmaf(r_lds[wid][1][k], w, o1);
    }
    const float b = bv[lane];
    out[(size_t)q0 * LDIM + lane] = (D0 > 0.0f) ? o0 + b : 0.0f;
    if (q0 + 1 < Nq)
        out[(size_t)(q0 + 1) * LDIM + lane] = (D1 > 0.0f) ? o1 + b : 0.0f;
}

extern "C" void kernel_launch(void* const* d_in, const int* in_sizes, int n_in,
                              void* d_out, int out_size, void* d_ws, size_t ws_size,
                              hipStream_t stream) {
    const float* h_obs     = (const float*)d_in[0];
    const float* pos_obs   = (const float*)d_in[1];
    const float* pos_query = (const float*)d_in[2];
    const float* W1        = (const float*)d_in[3];
    const float* b1        = (const float*)d_in[4];
    const float* W2        = (const float*)d_in[5];
    // d_in[6] = b2: constant shift, cancels in softmax -> unused
    const float* Wv        = (const float*)d_in[7];
    const float* bv        = (const float*)d_in[8];
    const int* obs_mask    = (const int*)d_in[9];
    const int* obs_batch   = (const int*)d_in[10];
    const int* query_batch = (const int*)d_in[11];

    const int No  = in_sizes[1] / 3;
    const int Nq  = in_sizes[2] / 3;
    const int NoA = (No + 63) & ~63;
    const int nC  = NoA / 64;
    const int nQT = (Nq + QTW - 1) / QTW;
    const int zn  = Nq * (LDIM + 1);

    // ws layout (~1.1 MB)
    float4* Bi   = (float4*)d_ws;                    // NoA*16 float4
    float4* A4   = Bi + (size_t)NoA * 16;            // Nq*16 float4
    float4* P4   = A4 + (size_t)Nq * 16;             // NoA float4
    float4* w2s4 = P4 + NoA;                         // 16 float4
    int2*   qwin = (int2*)(w2s4 + 16);               // nQT int2
    float*  acc  = (float*)(qwin + nQT);             // Nq*64 f (zeroed)
    float*  den  = acc + (size_t)Nq * LDIM;          // Nq f    (zeroed)

    int gridN = NoA * 16;
    if (Nq * 16 > gridN) gridN = Nq * 16;
    if (zn > gridN) gridN = zn;

    gano_pre<<<(gridN + 255) / 256, 256, 0, stream>>>(
        pos_obs, pos_query, W1, b1, W2, obs_mask, obs_batch, query_batch,
        Bi, A4, P4, w2s4, qwin, acc, No, NoA, Nq, nC, nQT, zn);

    dim3 g2(WSLOT, nQT);
    gano_accum<<<g2, 256, 0, stream>>>(
        h_obs, Bi, A4, P4, w2s4, pos_query, query_batch, qwin,
        acc, den, No, Nq);

    gano_norm<<<(Nq + 7) / 8, 256, 0, stream>>>(acc, den, Wv, bv, (float*)d_out, Nq);
}